// Round 10
// baseline (160.287 us; speedup 1.0000x reference)
//
#include <hip/hip_runtime.h>
#include <hip/hip_bf16.h>

// DIAGNOSTIC ROUND: R9 kernels, each body repeated in-kernel (idempotent) so
// both appear in rocprof top-5 with per-dispatch counters. Per-iteration
// codegen identical to R9 (asm memory clobber between iterations only).
// proj x24, pair x12. Output unchanged/correct; dur_us intentionally inflated.

#define IN_DIM 1600
#define H1D 64
#define H2D 32
#define NROW 512
#define NTOT 1024
#define KC_TOT 50   // 1600/32 k-chunks
#define KQ 8        // proj k-split (partials)
#define REPEAT_P 24
#define REPEAT_C 12

typedef short bf16x8 __attribute__((ext_vector_type(8)));
typedef float f32x4 __attribute__((ext_vector_type(4)));

static __device__ __forceinline__ unsigned short f2bf_u(float v) {
  __hip_bfloat16 h = __float2bfloat16(v);
  return *reinterpret_cast<unsigned short*>(&h);
}
static __device__ __forceinline__ float bf2f(unsigned short u) {
  __hip_bfloat16 h = *reinterpret_cast<__hip_bfloat16*>(&u);
  return __bfloat162float(h);
}
struct BfPair { short hi, lo; };
static __device__ __forceinline__ BfPair splitbf(float v) {
  BfPair p;
  const unsigned short h = f2bf_u(v);
  p.hi = (short)h;
  p.lo = (short)f2bf_u(v - bf2f(h));
  return p;
}

// ---------------- K1: projection via MFMA, fused bf16 split ----------------
__global__ __launch_bounds__(256) void proj_kernel(
    const float* __restrict__ x, const float* __restrict__ y,
    const float* __restrict__ W1, float* __restrict__ PTp) {
  const int tid = threadIdx.x, lane = tid & 63;
  const int mt = tid >> 6;
  const int l15 = lane & 15, l4 = lane >> 4;
  const int nc = (int)blockIdx.x >> 3;
  const int q = (int)blockIdx.x & 7;
  const int kc0 = (q * KC_TOT) >> 3, kc1 = ((q + 1) * KC_TOT) >> 3;

  const int hrow = mt * 16 + l15;
  const int xrow = nc * 16 + l15;
  const float* __restrict__ xs =
      (xrow < NROW) ? (x + (size_t)xrow * IN_DIM)
                    : (y + (size_t)(xrow - NROW) * IN_DIM);

  for (int rep = 0; rep < REPEAT_P; ++rep) {
    f32x4 aA = {0.f, 0.f, 0.f, 0.f};
    f32x4 aB = {0.f, 0.f, 0.f, 0.f};
    f32x4 aC = {0.f, 0.f, 0.f, 0.f};
    for (int kc = kc0; kc < kc1; ++kc) {
      const int kb = kc * 32 + l4 * 8;
      const float4 v0 = *reinterpret_cast<const float4*>(xs + kb);
      const float4 v1 = *reinterpret_cast<const float4*>(xs + kb + 4);
      bf16x8 xh, xl;
      {
        BfPair p;
        p = splitbf(v0.x); xh[0] = p.hi; xl[0] = p.lo;
        p = splitbf(v0.y); xh[1] = p.hi; xl[1] = p.lo;
        p = splitbf(v0.z); xh[2] = p.hi; xl[2] = p.lo;
        p = splitbf(v0.w); xh[3] = p.hi; xl[3] = p.lo;
        p = splitbf(v1.x); xh[4] = p.hi; xl[4] = p.lo;
        p = splitbf(v1.y); xh[5] = p.hi; xl[5] = p.lo;
        p = splitbf(v1.z); xh[6] = p.hi; xl[6] = p.lo;
        p = splitbf(v1.w); xh[7] = p.hi; xl[7] = p.lo;
      }
      bf16x8 wh, wl;
#pragma unroll
      for (int j = 0; j < 8; ++j) {
        const BfPair p = splitbf(W1[(size_t)(kb + j) * H1D + hrow]);
        wh[j] = p.hi; wl[j] = p.lo;
      }
      aA = __builtin_amdgcn_mfma_f32_16x16x32_bf16(wh, xh, aA, 0, 0, 0);
      aB = __builtin_amdgcn_mfma_f32_16x16x32_bf16(wl, xh, aB, 0, 0, 0);
      aC = __builtin_amdgcn_mfma_f32_16x16x32_bf16(wh, xl, aC, 0, 0, 0);
    }
#pragma unroll
    for (int r = 0; r < 4; ++r) {
      const int h = mt * 16 + l4 * 4 + r;
      PTp[((size_t)q * H1D + h) * NTOT + nc * 16 + l15] = aA[r] + aB[r] + aC[r];
    }
    asm volatile("" ::: "memory");   // keep iterations distinct (no DCE/hoist)
  }
}

// ---------------- K2: pair tiles via MFMA ----------------
__global__ __launch_bounds__(256) void pair_kernel(
    const float* __restrict__ PTp, const float* __restrict__ b1,
    const float* __restrict__ W2, const float* __restrict__ b2,
    const float* __restrict__ W3, const float* __restrict__ b3,
    float* __restrict__ out) {
  __shared__ float sX[16][68];
  __shared__ float sY[16][68];
  __shared__ float sO[16][16];

  const int tid = threadIdx.x;
  const int wave = tid >> 6, lane = tid & 63;
  const int l15 = lane & 15, l4 = lane >> 4;
  const int wb = blockIdx.x * 16, qb = blockIdx.y * 16;

  for (int rep = 0; rep < REPEAT_C; ++rep) {
    {  // stage: sX[r][h] = sum_q PTp[q][h][wb+r] + b1[h]; sY same from y cols
      const int h = tid >> 2, r0 = (tid & 3) << 2;
      f32x4 sx = {0.f, 0.f, 0.f, 0.f}, sy = {0.f, 0.f, 0.f, 0.f};
#pragma unroll
      for (int q = 0; q < KQ; ++q) {
        sx += *reinterpret_cast<const f32x4*>(&PTp[((size_t)q * H1D + h) * NTOT + wb + r0]);
        sy += *reinterpret_cast<const f32x4*>(&PTp[((size_t)q * H1D + h) * NTOT + NROW + qb + r0]);
      }
      const float b1h = b1[h];
#pragma unroll
      for (int i = 0; i < 4; ++i) {
        sX[r0 + i][h] = sx[i] + b1h;
        sY[r0 + i][h] = sy[i];
      }
    }

    bf16x8 bfr[2][2];
#pragma unroll
    for (int nt = 0; nt < 2; ++nt)
#pragma unroll
      for (int ks = 0; ks < 2; ++ks)
#pragma unroll
        for (int j = 0; j < 8; ++j)
          bfr[nt][ks][j] = (short)f2bf_u(W2[(ks * 32 + l4 * 8 + j) * H2D + nt * 16 + l15]);
    const float b2v0 = b2[l15], b2v1 = b2[16 + l15];
    const float w3v0 = W3[l15], w3v1 = W3[16 + l15];
    const float b3v = b3[0];

    f32x4 acc[4][2];
#pragma unroll
    for (int mt = 0; mt < 4; ++mt)
#pragma unroll
      for (int r = 0; r < 4; ++r) { acc[mt][0][r] = b2v0; acc[mt][1][r] = b2v1; }

    __syncthreads();

#pragma unroll
    for (int ks = 0; ks < 2; ++ks) {
      const int kb = ks * 32 + l4 * 8;
      const float4 y0 = *reinterpret_cast<const float4*>(&sY[l15][kb]);
      const float4 y1 = *reinterpret_cast<const float4*>(&sY[l15][kb + 4]);
#pragma unroll
      for (int mt = 0; mt < 4; ++mt) {
        const int lw = wave * 4 + mt;
        const float4 x0 = *reinterpret_cast<const float4*>(&sX[lw][kb]);
        const float4 x1 = *reinterpret_cast<const float4*>(&sX[lw][kb + 4]);
        bf16x8 af; float v;
        v = x0.x - y0.x; af[0] = (short)f2bf_u(v > 0.f ? v : 0.f);
        v = x0.y - y0.y; af[1] = (short)f2bf_u(v > 0.f ? v : 0.f);
        v = x0.z - y0.z; af[2] = (short)f2bf_u(v > 0.f ? v : 0.f);
        v = x0.w - y0.w; af[3] = (short)f2bf_u(v > 0.f ? v : 0.f);
        v = x1.x - y1.x; af[4] = (short)f2bf_u(v > 0.f ? v : 0.f);
        v = x1.y - y1.y; af[5] = (short)f2bf_u(v > 0.f ? v : 0.f);
        v = x1.z - y1.z; af[6] = (short)f2bf_u(v > 0.f ? v : 0.f);
        v = x1.w - y1.w; af[7] = (short)f2bf_u(v > 0.f ? v : 0.f);
        acc[mt][0] = __builtin_amdgcn_mfma_f32_16x16x32_bf16(af, bfr[0][ks], acc[mt][0], 0, 0, 0);
        acc[mt][1] = __builtin_amdgcn_mfma_f32_16x16x32_bf16(af, bfr[1][ks], acc[mt][1], 0, 0, 0);
      }
    }

#pragma unroll
    for (int mt = 0; mt < 4; ++mt) {
      float t[4];
#pragma unroll
      for (int r = 0; r < 4; ++r) {
        const float q0 = acc[mt][0][r] > 0.f ? acc[mt][0][r] : 0.f;
        const float q1 = acc[mt][1][r] > 0.f ? acc[mt][1][r] : 0.f;
        t[r] = fmaf(q0, w3v0, q1 * w3v1);
      }
#pragma unroll
      for (int off = 1; off < 16; off <<= 1) {
#pragma unroll
        for (int r = 0; r < 4; ++r) t[r] += __shfl_xor(t[r], off, 64);
      }
      if (l15 == 0) {
#pragma unroll
        for (int r = 0; r < 4; ++r) {
          const float o = t[r] + b3v;
          sO[wave * 4 + mt][l4 * 4 + r] = o > 0.f ? o : 0.f;
        }
      }
    }
    __syncthreads();
    out[(size_t)(wb + (tid >> 4)) * NROW + qb + (tid & 15)] = sO[tid >> 4][tid & 15];
    __syncthreads();                 // protect sX/sY restage of next iteration
    asm volatile("" ::: "memory");   // keep iterations distinct
  }
}

extern "C" void kernel_launch(void* const* d_in, const int* in_sizes, int n_in,
                              void* d_out, int out_size, void* d_ws, size_t ws_size,
                              hipStream_t stream) {
  const float* x  = (const float*)d_in[0];
  const float* y  = (const float*)d_in[1];
  const float* W1 = (const float*)d_in[2];
  const float* b1 = (const float*)d_in[3];
  const float* W2 = (const float*)d_in[4];
  const float* b2 = (const float*)d_in[5];
  const float* W3 = (const float*)d_in[6];
  const float* b3 = (const float*)d_in[7];
  float* out = (float*)d_out;

  float* PTp = (float*)d_ws;   // KQ*64*1024*4 = 2 MB

  proj_kernel<<<512, 256, 0, stream>>>(x, y, W1, PTp);
  pair_kernel<<<dim3(32, 32), 256, 0, stream>>>(PTp, b1, W2, b2, W3, b3, out);
}

// Round 11
// 20.605 us; speedup vs baseline: 7.7789x; 7.7789x over previous
//
#include <hip/hip_runtime.h>
#include <hip/hip_bf16.h>

// MLP_64450279244218: o[w][q] = relu(relu(relu((x[w]-y[q])@W1+b1)@W2+b2)@W3+b3)
// (x-y)@W1 = x@W1 - y@W1 -> projections computed once.
// TWO nodes (inter-node gap ~5us; device-side sync refuted R5/R6):
// K1 proj: PTp[8][64][1024] partials via mfma_f32_16x16x32_bf16 with in-kernel
//          bf16 hi/lo 3-term split. R10 diag: 4.5us/iter, VALU 33%, stall 67%
//          -> cause: runtime kc-loop bounds blocked full unroll. Fix: dispatch
//          compile-time trip counts (6 or 7) -> ~60 loads in flight.
// K2 pair: 16x16 pair tile (validated R3/R7/R9, <=3.3us): stage sX/sY summing
//          8 partials (+b1), h1 -> bf16 A-frags, layer-2 MFMA, layer-3 fp32
//          shfl-reduce.

#define IN_DIM 1600
#define H1D 64
#define H2D 32
#define NROW 512
#define NTOT 1024
#define KC_TOT 50   // 1600/32 k-chunks
#define KQ 8        // proj k-split (partials)

typedef short bf16x8 __attribute__((ext_vector_type(8)));
typedef float f32x4 __attribute__((ext_vector_type(4)));

static __device__ __forceinline__ unsigned short f2bf_u(float v) {
  __hip_bfloat16 h = __float2bfloat16(v);
  return *reinterpret_cast<unsigned short*>(&h);
}
static __device__ __forceinline__ float bf2f(unsigned short u) {
  __hip_bfloat16 h = *reinterpret_cast<__hip_bfloat16*>(&u);
  return __bfloat162float(h);
}
struct BfPair { short hi, lo; };
static __device__ __forceinline__ BfPair splitbf(float v) {
  BfPair p;
  const unsigned short h = f2bf_u(v);
  p.hi = (short)h;
  p.lo = (short)f2bf_u(v - bf2f(h));
  return p;
}

// ---- proj inner loop, compile-time trip count for full unroll ----
// xs: x-row base; wcol: W1 column base (= W1 + hrow), strided 64 floats/k.
template <int CNT>
static __device__ __forceinline__ void proj_accum(
    const float* __restrict__ xs, const float* __restrict__ wcol,
    int kc0, int l4, f32x4& aA, f32x4& aB, f32x4& aC) {
#pragma unroll
  for (int i = 0; i < CNT; ++i) {
    const int kb = (kc0 + i) * 32 + l4 * 8;
    const float4 v0 = *reinterpret_cast<const float4*>(xs + kb);
    const float4 v1 = *reinterpret_cast<const float4*>(xs + kb + 4);
    bf16x8 xh, xl;
    {
      BfPair p;
      p = splitbf(v0.x); xh[0] = p.hi; xl[0] = p.lo;
      p = splitbf(v0.y); xh[1] = p.hi; xl[1] = p.lo;
      p = splitbf(v0.z); xh[2] = p.hi; xl[2] = p.lo;
      p = splitbf(v0.w); xh[3] = p.hi; xl[3] = p.lo;
      p = splitbf(v1.x); xh[4] = p.hi; xl[4] = p.lo;
      p = splitbf(v1.y); xh[5] = p.hi; xl[5] = p.lo;
      p = splitbf(v1.z); xh[6] = p.hi; xl[6] = p.lo;
      p = splitbf(v1.w); xh[7] = p.hi; xl[7] = p.lo;
    }
    bf16x8 wh, wl;
#pragma unroll
    for (int j = 0; j < 8; ++j) {
      const BfPair p = splitbf(wcol[(size_t)(kb + j) * H1D]);
      wh[j] = p.hi; wl[j] = p.lo;
    }
    aA = __builtin_amdgcn_mfma_f32_16x16x32_bf16(wh, xh, aA, 0, 0, 0);
    aB = __builtin_amdgcn_mfma_f32_16x16x32_bf16(wl, xh, aB, 0, 0, 0);
    aC = __builtin_amdgcn_mfma_f32_16x16x32_bf16(wh, xl, aC, 0, 0, 0);
  }
}

// ---------------- K1: projection via MFMA, fused bf16 split ----------------
// A = W1T (frag row = h), B = X (frag col = x-row). C row(h)=l4*4+r, col=l15.
__global__ __launch_bounds__(256) void proj_kernel(
    const float* __restrict__ x, const float* __restrict__ y,
    const float* __restrict__ W1, float* __restrict__ PTp) {
  const int tid = threadIdx.x, lane = tid & 63;
  const int mt = tid >> 6;                       // wave = m-tile 0..3
  const int l15 = lane & 15, l4 = lane >> 4;
  const int nc = (int)blockIdx.x >> 3;           // row-chunk 0..63 (16 rows)
  const int q = (int)blockIdx.x & 7;             // k-eighth
  const int kc0 = (q * KC_TOT) >> 3, kc1 = ((q + 1) * KC_TOT) >> 3;

  const int hrow = mt * 16 + l15;                // A-frag row (h)
  const int xrow = nc * 16 + l15;                // B-frag col (x-row)
  const float* __restrict__ xs =
      (xrow < NROW) ? (x + (size_t)xrow * IN_DIM)
                    : (y + (size_t)(xrow - NROW) * IN_DIM);
  const float* __restrict__ wcol = W1 + hrow;

  f32x4 aA = {0.f, 0.f, 0.f, 0.f};
  f32x4 aB = {0.f, 0.f, 0.f, 0.f};
  f32x4 aC = {0.f, 0.f, 0.f, 0.f};
  if (kc1 - kc0 == 7)
    proj_accum<7>(xs, wcol, kc0, l4, aA, aB, aC);
  else
    proj_accum<6>(xs, wcol, kc0, l4, aA, aB, aC);

#pragma unroll
  for (int r = 0; r < 4; ++r) {                  // C: row(h)=l4*4+r, col=l15
    const int h = mt * 16 + l4 * 4 + r;
    PTp[((size_t)q * H1D + h) * NTOT + nc * 16 + l15] = aA[r] + aB[r] + aC[r];
  }
}

// ---------------- K2: pair tiles via MFMA (validated body) ----------------
__global__ __launch_bounds__(256) void pair_kernel(
    const float* __restrict__ PTp, const float* __restrict__ b1,
    const float* __restrict__ W2, const float* __restrict__ b2,
    const float* __restrict__ W3, const float* __restrict__ b3,
    float* __restrict__ out) {
  __shared__ float sX[16][68];   // 272B row stride -> b128 conflict-free
  __shared__ float sY[16][68];
  __shared__ float sO[16][16];

  const int tid = threadIdx.x;
  const int wave = tid >> 6, lane = tid & 63;
  const int l15 = lane & 15, l4 = lane >> 4;
  const int wb = blockIdx.x * 16, qb = blockIdx.y * 16;

  {  // stage: sX[r][h] = sum_q PTp[q][h][wb+r] + b1[h]; sY same from y cols
    const int h = tid >> 2, r0 = (tid & 3) << 2;
    f32x4 sx = {0.f, 0.f, 0.f, 0.f}, sy = {0.f, 0.f, 0.f, 0.f};
#pragma unroll
    for (int q = 0; q < KQ; ++q) {
      sx += *reinterpret_cast<const f32x4*>(&PTp[((size_t)q * H1D + h) * NTOT + wb + r0]);
      sy += *reinterpret_cast<const f32x4*>(&PTp[((size_t)q * H1D + h) * NTOT + NROW + qb + r0]);
    }
    const float b1h = b1[h];
#pragma unroll
    for (int i = 0; i < 4; ++i) {   // 2-way bank aliasing only (free)
      sX[r0 + i][h] = sx[i] + b1h;
      sY[r0 + i][h] = sy[i];
    }
  }

  // B fragments (W2) direct from global (8KB, L1/L2-hot)
  bf16x8 bfr[2][2];
#pragma unroll
  for (int nt = 0; nt < 2; ++nt)
#pragma unroll
    for (int ks = 0; ks < 2; ++ks)
#pragma unroll
      for (int j = 0; j < 8; ++j)
        bfr[nt][ks][j] = (short)f2bf_u(W2[(ks * 32 + l4 * 8 + j) * H2D + nt * 16 + l15]);
  const float b2v0 = b2[l15], b2v1 = b2[16 + l15];
  const float w3v0 = W3[l15], w3v1 = W3[16 + l15];
  const float b3v = b3[0];

  f32x4 acc[4][2];
#pragma unroll
  for (int mt = 0; mt < 4; ++mt)
#pragma unroll
    for (int r = 0; r < 4; ++r) { acc[mt][0][r] = b2v0; acc[mt][1][r] = b2v1; }

  __syncthreads();

  // A fragments: row = l15 (y idx), k = ks*32 + l4*8 + j ; value = relu(Px-Py)
#pragma unroll
  for (int ks = 0; ks < 2; ++ks) {
    const int kb = ks * 32 + l4 * 8;
    const float4 y0 = *reinterpret_cast<const float4*>(&sY[l15][kb]);
    const float4 y1 = *reinterpret_cast<const float4*>(&sY[l15][kb + 4]);
#pragma unroll
    for (int mt = 0; mt < 4; ++mt) {
      const int lw = wave * 4 + mt;
      const float4 x0 = *reinterpret_cast<const float4*>(&sX[lw][kb]);
      const float4 x1 = *reinterpret_cast<const float4*>(&sX[lw][kb + 4]);
      bf16x8 af; float v;
      v = x0.x - y0.x; af[0] = (short)f2bf_u(v > 0.f ? v : 0.f);
      v = x0.y - y0.y; af[1] = (short)f2bf_u(v > 0.f ? v : 0.f);
      v = x0.z - y0.z; af[2] = (short)f2bf_u(v > 0.f ? v : 0.f);
      v = x0.w - y0.w; af[3] = (short)f2bf_u(v > 0.f ? v : 0.f);
      v = x1.x - y1.x; af[4] = (short)f2bf_u(v > 0.f ? v : 0.f);
      v = x1.y - y1.y; af[5] = (short)f2bf_u(v > 0.f ? v : 0.f);
      v = x1.z - y1.z; af[6] = (short)f2bf_u(v > 0.f ? v : 0.f);
      v = x1.w - y1.w; af[7] = (short)f2bf_u(v > 0.f ? v : 0.f);
      acc[mt][0] = __builtin_amdgcn_mfma_f32_16x16x32_bf16(af, bfr[0][ks], acc[mt][0], 0, 0, 0);
      acc[mt][1] = __builtin_amdgcn_mfma_f32_16x16x32_bf16(af, bfr[1][ks], acc[mt][1], 0, 0, 0);
    }
  }

  // layer 3: o = relu(sum_n relu(h2[n]) * W3[n] + b3), reduce 16 n-lanes
#pragma unroll
  for (int mt = 0; mt < 4; ++mt) {
    float t[4];
#pragma unroll
    for (int r = 0; r < 4; ++r) {
      const float q0 = acc[mt][0][r] > 0.f ? acc[mt][0][r] : 0.f;
      const float q1 = acc[mt][1][r] > 0.f ? acc[mt][1][r] : 0.f;
      t[r] = fmaf(q0, w3v0, q1 * w3v1);
    }
#pragma unroll
    for (int off = 1; off < 16; off <<= 1) {
#pragma unroll
      for (int r = 0; r < 4; ++r) t[r] += __shfl_xor(t[r], off, 64);
    }
    if (l15 == 0) {
#pragma unroll
      for (int r = 0; r < 4; ++r) {
        const float o = t[r] + b3v;
        sO[wave * 4 + mt][l4 * 4 + r] = o > 0.f ? o : 0.f;   // [lw][lq]
      }
    }
  }
  __syncthreads();
  out[(size_t)(wb + (tid >> 4)) * NROW + qb + (tid & 15)] = sO[tid >> 4][tid & 15];
}

extern "C" void kernel_launch(void* const* d_in, const int* in_sizes, int n_in,
                              void* d_out, int out_size, void* d_ws, size_t ws_size,
                              hipStream_t stream) {
  const float* x  = (const float*)d_in[0];
  const float* y  = (const float*)d_in[1];
  const float* W1 = (const float*)d_in[2];
  const float* b1 = (const float*)d_in[3];
  const float* W2 = (const float*)d_in[4];
  const float* b2 = (const float*)d_in[5];
  const float* W3 = (const float*)d_in[6];
  const float* b3 = (const float*)d_in[7];
  float* out = (float*)d_out;

  float* PTp = (float*)d_ws;   // KQ*64*1024*4 = 2 MB

  proj_kernel<<<512, 256, 0, stream>>>(x, y, W1, PTp);   // 64 nc x 8 q
  pair_kernel<<<dim3(32, 32), 256, 0, stream>>>(PTp, b1, W2, b2, W3, b3, out);
}